// Round 3
// baseline (46344.794 us; speedup 1.0000x reference)
//
#include <hip/hip_runtime.h>
#include <hip/hip_bf16.h>

#define N_NODES 10000
#define N_EDGES 160000
#define FEAT_W 320
#define CHUNK 16

__device__ __forceinline__ float gelu_tanh(float x) {
    float x3 = x * x * x;
    float t = tanhf(0.7978845608028654f * (x + 0.044715f * x3));
    return 0.5f * x * (1.0f + t);
}

// ---------------- Kernel 1: node transforms (feat0/feat1/self0/self1) -------
// feat_tbl / self_tbl rows: [0..128) = mul0 part, [128..320) = mul1 part as u*3+i
__global__ __launch_bounds__(256) void node_transform(
    const float* __restrict__ node_input,
    const float* __restrict__ Wa0, const float* __restrict__ Wa1,
    const float* __restrict__ Wb0, const float* __restrict__ Wb1,
    float* __restrict__ feat_tbl, float* __restrict__ self_tbl)
{
    __shared__ float x[FEAT_W];
    const int node = blockIdx.x;
    const float* row = node_input + (size_t)node * FEAT_W;
    for (int t = threadIdx.x; t < FEAT_W; t += 256) x[t] = row[t];
    __syncthreads();

    for (int t = threadIdx.x; t < 640; t += 256) {
        const bool is_self = (t >= 320);
        const int idx = is_self ? t - 320 : t;
        float acc = 0.f;
        if (idx < 128) {
            const float* W = is_self ? Wb0 : Wa0;
            for (int v = 0; v < 128; ++v) acc += x[v] * W[v * 128 + idx];
            acc *= 0.08838834764831845f;  // 1/sqrt(128)
        } else {
            const int r = idx - 128;
            const int u = r / 3;
            const int i = r - 3 * u;
            const float* W = is_self ? Wb1 : Wa1;
            for (int v = 0; v < 64; ++v) acc += x[128 + v * 3 + i] * W[v * 64 + u];
            acc *= 0.125f;  // 1/sqrt(64)
        }
        float* outp = is_self ? self_tbl : feat_tbl;
        outp[(size_t)node * FEAT_W + idx] = acc;
    }
}

// ---------------- Kernel 2: per-edge MLP -> h2 ------------------------------
__global__ __launch_bounds__(256) void mlp_kernel(
    const float* __restrict__ esa,   // (E,8)
    const float* __restrict__ M1,    // (8,64)
    const float* __restrict__ M2,    // (64,64)
    float* __restrict__ h2buf)       // (E,64)
{
    __shared__ float sh[4][64];
    const int wave = threadIdx.x >> 6;
    const int lane = threadIdx.x & 63;
    const int e = blockIdx.x * 4 + wave;   // N_EDGES % 4 == 0

    const float* er = esa + (size_t)e * 8;
    float h = 0.f;
#pragma unroll
    for (int k = 0; k < 8; ++k) h += er[k] * M1[k * 64 + lane];
    h = gelu_tanh(h * 0.35355339059327373f);   // 1/sqrt(8)
    sh[wave][lane] = h;
    __syncthreads();

    float h2 = 0.f;
    for (int v = 0; v < 64; ++v) h2 += sh[wave][v] * M2[v * 64 + lane];
    h2 = gelu_tanh(h2 * 0.125f);               // 1/sqrt(64)
    h2buf[(size_t)e * 64 + lane] = h2;
}

// ---------------- CSR build -------------------------------------------------
__global__ void count_kernel(const int* __restrict__ edge_dst, int* __restrict__ counts) {
    int e = blockIdx.x * 256 + threadIdx.x;
    if (e < N_EDGES) atomicAdd(&counts[edge_dst[e]], 1);
}

__global__ __launch_bounds__(1024) void scan_kernel(
    const int* __restrict__ counts, int* __restrict__ offsets, int* __restrict__ cursor)
{
    __shared__ int buf[1024];
    int base = 0;
    for (int c = 0; c < 10; ++c) {            // 10*1024 >= 10000
        int i = c * 1024 + threadIdx.x;
        int v = (i < N_NODES) ? counts[i] : 0;
        buf[threadIdx.x] = v;
        __syncthreads();
        for (int off = 1; off < 1024; off <<= 1) {
            int t = (threadIdx.x >= off) ? buf[threadIdx.x - off] : 0;
            __syncthreads();
            buf[threadIdx.x] += t;
            __syncthreads();
        }
        int excl = buf[threadIdx.x] - v;
        if (i < N_NODES) { offsets[i] = base + excl; cursor[i] = base + excl; }
        int tot = buf[1023];
        __syncthreads();
        base += tot;
    }
    if (threadIdx.x == 0) offsets[N_NODES] = base;
}

__global__ void fill_kernel(const int* __restrict__ edge_dst,
                            int* __restrict__ cursor, int* __restrict__ elist) {
    int e = blockIdx.x * 256 + threadIdx.x;
    if (e < N_EDGES) {
        int pos = atomicAdd(&cursor[edge_dst[e]], 1);
        elist[pos] = e;
    }
}

// ---------------- Kernel 3: per-node gather + TP + output GEMM --------------
// one block per node; atomic-free accumulation; fuses out_kernel
__global__ __launch_bounds__(256) void gather_kernel(
    const int* __restrict__ offsets, const int* __restrict__ elist,
    const int* __restrict__ edge_src,
    const float* __restrict__ edge_attr,   // (E,4)
    const float* __restrict__ h2buf,       // (E,64)
    const float* __restrict__ feat_tbl,    // (N,320)
    const float* __restrict__ self_tbl,    // (N,320)
    const float* __restrict__ Wtp0,        // (64,128)
    const float* __restrict__ Wtp1,        // (64,128)
    const float* __restrict__ Wtp2,        // (64,64)
    const float* __restrict__ Wtp3,        // (64,64)
    const float* __restrict__ Wo0,         // (192,128)
    const float* __restrict__ Wo1,         // (192,64)
    float* __restrict__ out)               // (N,320)
{
    __shared__ float h2s[CHUNK][65];       // +1 pad: conflict-free k-reads
    __shared__ float Ws[384 * 17];         // W[u][e] at u*17+e (17 = CHUNK+1 pad)
    __shared__ float fs[CHUNK][321];       // feat rows, +1 pad
    __shared__ float ys[CHUNK][4];
    __shared__ int   eids[CHUNK];
    __shared__ int   srcs[CHUNK];
    __shared__ float z[768];

    const int node = blockIdx.x;
    const int t = threadIdx.x;

    // ---- per-thread output mapping for j in {t, t+256, t+512} ----
    // kind: 0=mid0a(w0*e0*y0) 1=mid0b(w3*dot/sqrt3) 2=mid1a(w1*e0*y1i) 3=mid1b(w2*e1i*y0)
    int wrow0, fidx0, yidx0, kind0;
    if (t < 128)      { kind0 = 0; wrow0 = t;                 fidx0 = t;   yidx0 = 0; }
    else if (t < 192) { kind0 = 1; wrow0 = 320 + (t - 128);   fidx0 = 128 + 3 * (t - 128); yidx0 = 0; }
    else { int r = t - 192, u = r / 3, i = r - 3 * u;
           kind0 = 2; wrow0 = 128 + u; fidx0 = u; yidx0 = 1 + i; }
    int r1 = t + 64, u1 = r1 / 3, i1 = r1 - 3 * u1;          // j1 = t+256, always mid1a
    const int wrow1 = 128 + u1, fidx1 = u1, yidx1 = 1 + i1;
    int wrow2, fidx2, yidx2;                                  // j2 = t+512
    if (t < 64) { int r = t + 320, u = r / 3, i = r - 3 * u;  // mid1a tail
                  wrow2 = 128 + u; fidx2 = u; yidx2 = 1 + i; }
    else        { int r = t - 64,  u = r / 3, i = r - 3 * u;  // mid1b
                  wrow2 = 256 + u; fidx2 = 128 + 3 * u + i; yidx2 = 0; }

    float acc0 = 0.f, acc1 = 0.f, acc2 = 0.f;
    const int beg = offsets[node], end = offsets[node + 1];

    for (int cb = beg; cb < end; cb += CHUNK) {
        const int ne = min(CHUNK, end - cb);
        if (t < ne) eids[t] = elist[cb + t];
        __syncthreads();
        if (t < ne) srcs[t] = edge_src[eids[t]];
        // stage h2 rows
        for (int x = t; x < ne * 64; x += 256) {
            int e = x >> 6, k = x & 63;
            h2s[e][k] = h2buf[(size_t)eids[e] * 64 + k];
        }
        // stage y
        for (int x = t; x < ne * 4; x += 256) {
            int e = x >> 2, i = x & 3;
            ys[e][i] = edge_attr[(size_t)eids[e] * 4 + i];
        }
        __syncthreads();
        // stage feat rows (needs srcs)
        for (int x = t; x < ne * 320; x += 256) {
            int e = x / 320, k = x - e * 320;
            fs[e][k] = feat_tbl[(size_t)srcs[e] * FEAT_W + k];
        }
        __syncthreads();

        // ---- W tile: w[e][u] = (h2[e] . Wtp?[:,u]) / 8, u in [0,384) ----
#pragma unroll
        for (int rep = 0; rep < 24; ++rep) {   // 24*256 = 6144 = 384*16
            int flat = rep * 256 + t;
            int u = flat >> 4, e = flat & 15;
            if (e < ne) {
                const float* col; int stride;
                if (u < 128)      { col = Wtp0 + u;         stride = 128; }
                else if (u < 256) { col = Wtp1 + (u - 128); stride = 128; }
                else if (u < 320) { col = Wtp2 + (u - 256); stride = 64;  }
                else              { col = Wtp3 + (u - 320); stride = 64;  }
                float s = 0.f;
                for (int k = 0; k < 64; ++k) s += h2s[e][k] * col[k * stride];
                Ws[u * 17 + e] = s * 0.125f;   // 1/sqrt(64)
            }
        }
        __syncthreads();

        // ---- accumulate tensor product ----
        for (int e = 0; e < ne; ++e) {
            const float y0 = ys[e][0];
            // j0
            if (kind0 == 1) {
                const float d = fs[e][fidx0] * ys[e][1] + fs[e][fidx0 + 1] * ys[e][2]
                              + fs[e][fidx0 + 2] * ys[e][3];
                acc0 += Ws[wrow0 * 17 + e] * d * 0.5773502691896258f;  // 1/sqrt(3)
            } else {
                acc0 += Ws[wrow0 * 17 + e] * fs[e][fidx0] * ys[e][yidx0];
            }
            // j1, j2
            acc1 += Ws[wrow1 * 17 + e] * fs[e][fidx1] * ys[e][yidx1];
            acc2 += Ws[wrow2 * 17 + e] * fs[e][fidx2] * ys[e][yidx2];
            (void)y0;
        }
        __syncthreads();   // before next chunk overwrites LDS
    }

    // ---- z row (includes 1/sqrt(16)) ----
    z[t]       = acc0 * 0.25f;
    z[t + 256] = acc1 * 0.25f;
    z[t + 512] = acc2 * 0.25f;
    __syncthreads();

    // ---- output GEMMs + rotation combine ----
    const float sA = 0.07216878364870323f;   // 1/sqrt(192)
    const float cR = 0.92387953251128674f;   // cos(pi/8)
    const float sR = 0.38268343236508978f;   // sin(pi/8)

    for (int jj = t; jj < 320; jj += 256) {
        float conv = 0.f;
        if (jj < 128) {
            for (int v = 0; v < 192; ++v) conv += z[v] * Wo0[v * 128 + jj];
        } else {
            const int r = jj - 128, u = r / 3, i = r - 3 * u;
            for (int v = 0; v < 128; ++v) conv += z[192 + v * 3 + i] * Wo1[v * 64 + u];
            for (int v = 0; v < 64; ++v)  conv += z[576 + v * 3 + i] * Wo1[(128 + v) * 64 + u];
        }
        conv *= sA;
        const float sv = self_tbl[(size_t)node * FEAT_W + jj];
        out[(size_t)node * FEAT_W + jj] = cR * sv + sR * conv;
    }
}

extern "C" void kernel_launch(void* const* d_in, const int* in_sizes, int n_in,
                              void* d_out, int out_size, void* d_ws, size_t ws_size,
                              hipStream_t stream) {
    const float* node_input = (const float*)d_in[0];
    const float* edge_attr  = (const float*)d_in[1];
    const float* esa        = (const float*)d_in[2];
    const float* Wa0  = (const float*)d_in[3];
    const float* Wa1  = (const float*)d_in[4];
    const float* Wb0  = (const float*)d_in[5];
    const float* Wb1  = (const float*)d_in[6];
    const float* M1   = (const float*)d_in[7];
    const float* M2   = (const float*)d_in[8];
    const float* Wtp0 = (const float*)d_in[9];
    const float* Wtp1 = (const float*)d_in[10];
    const float* Wtp2 = (const float*)d_in[11];
    const float* Wtp3 = (const float*)d_in[12];
    const float* Wo0  = (const float*)d_in[13];
    const float* Wo1  = (const float*)d_in[14];
    const int* edge_src = (const int*)d_in[15];
    const int* edge_dst = (const int*)d_in[16];
    float* out = (float*)d_out;

    float* feat_tbl = (float*)d_ws;                               // 10000*320
    float* self_tbl = feat_tbl + (size_t)N_NODES * FEAT_W;        // 10000*320
    float* h2buf    = self_tbl + (size_t)N_NODES * FEAT_W;        // 160000*64
    int*   counts   = (int*)(h2buf + (size_t)N_EDGES * 64);       // 10000
    int*   offsets  = counts + N_NODES;                           // 10001
    int*   cursor   = offsets + N_NODES + 1;                      // 10000
    int*   elist    = cursor + N_NODES;                           // 160000

    hipMemsetAsync(counts, 0, sizeof(int) * N_NODES, stream);

    node_transform<<<N_NODES, 256, 0, stream>>>(node_input, Wa0, Wa1, Wb0, Wb1,
                                                feat_tbl, self_tbl);
    mlp_kernel<<<N_EDGES / 4, 256, 0, stream>>>(esa, M1, M2, h2buf);
    count_kernel<<<(N_EDGES + 255) / 256, 256, 0, stream>>>(edge_dst, counts);
    scan_kernel<<<1, 1024, 0, stream>>>(counts, offsets, cursor);
    fill_kernel<<<(N_EDGES + 255) / 256, 256, 0, stream>>>(edge_dst, cursor, elist);
    gather_kernel<<<N_NODES, 256, 0, stream>>>(offsets, elist, edge_src,
                                               edge_attr, h2buf, feat_tbl, self_tbl,
                                               Wtp0, Wtp1, Wtp2, Wtp3, Wo0, Wo1, out);
}

// Round 4
// 1658.423 us; speedup vs baseline: 27.9451x; 27.9451x over previous
//
#include <hip/hip_runtime.h>
#include <hip/hip_bf16.h>

#define N_NODES 10000
#define N_EDGES 160000
#define FEAT_W 320
#define CHUNK 16

__device__ __forceinline__ float gelu_tanh(float x) {
    float x3 = x * x * x;
    float t = tanhf(0.7978845608028654f * (x + 0.044715f * x3));
    return 0.5f * x * (1.0f + t);
}

// ---------------- Kernel 1: node transforms (feat0/feat1/self0/self1) -------
// feat_tbl / self_tbl rows: [0..128) = mul0 part, [128..320) = mul1 part as u*3+i
__global__ __launch_bounds__(256) void node_transform(
    const float* __restrict__ node_input,
    const float* __restrict__ Wa0, const float* __restrict__ Wa1,
    const float* __restrict__ Wb0, const float* __restrict__ Wb1,
    float* __restrict__ feat_tbl, float* __restrict__ self_tbl)
{
    __shared__ float x[FEAT_W];
    const int node = blockIdx.x;
    const float* row = node_input + (size_t)node * FEAT_W;
    for (int t = threadIdx.x; t < FEAT_W; t += 256) x[t] = row[t];
    __syncthreads();

    for (int t = threadIdx.x; t < 640; t += 256) {
        const bool is_self = (t >= 320);
        const int idx = is_self ? t - 320 : t;
        float acc = 0.f;
        if (idx < 128) {
            const float* W = is_self ? Wb0 : Wa0;
            for (int v = 0; v < 128; ++v) acc += x[v] * W[v * 128 + idx];
            acc *= 0.08838834764831845f;  // 1/sqrt(128)
        } else {
            const int r = idx - 128;
            const int u = r / 3;
            const int i = r - 3 * u;
            const float* W = is_self ? Wb1 : Wa1;
            for (int v = 0; v < 64; ++v) acc += x[128 + v * 3 + i] * W[v * 64 + u];
            acc *= 0.125f;  // 1/sqrt(64)
        }
        float* outp = is_self ? self_tbl : feat_tbl;
        outp[(size_t)node * FEAT_W + idx] = acc;
    }
}

// ---------------- Kernel 2: per-edge MLP -> h2 ------------------------------
__global__ __launch_bounds__(256) void mlp_kernel(
    const float* __restrict__ esa,   // (E,8)
    const float* __restrict__ M1,    // (8,64)
    const float* __restrict__ M2,    // (64,64)
    float* __restrict__ h2buf)       // (E,64)
{
    __shared__ float sh[4][64];
    const int wave = threadIdx.x >> 6;
    const int lane = threadIdx.x & 63;
    const int e = blockIdx.x * 4 + wave;   // N_EDGES % 4 == 0

    const float* er = esa + (size_t)e * 8;
    float h = 0.f;
#pragma unroll
    for (int k = 0; k < 8; ++k) h += er[k] * M1[k * 64 + lane];
    h = gelu_tanh(h * 0.35355339059327373f);   // 1/sqrt(8)
    sh[wave][lane] = h;
    __syncthreads();

    float h2 = 0.f;
    for (int v = 0; v < 64; ++v) h2 += sh[wave][v] * M2[v * 64 + lane];
    h2 = gelu_tanh(h2 * 0.125f);               // 1/sqrt(64)
    h2buf[(size_t)e * 64 + lane] = h2;
}

// ---------------- CSR build -------------------------------------------------
__global__ void count_kernel(const int* __restrict__ edge_dst, int* __restrict__ counts) {
    int e = blockIdx.x * 256 + threadIdx.x;
    if (e < N_EDGES) atomicAdd(&counts[edge_dst[e]], 1);
}

__global__ __launch_bounds__(1024) void scan_kernel(
    const int* __restrict__ counts, int* __restrict__ offsets, int* __restrict__ cursor)
{
    __shared__ int buf[1024];
    int base = 0;
    for (int c = 0; c < 10; ++c) {            // 10*1024 >= 10000
        int i = c * 1024 + threadIdx.x;
        int v = (i < N_NODES) ? counts[i] : 0;
        buf[threadIdx.x] = v;
        __syncthreads();
        for (int off = 1; off < 1024; off <<= 1) {
            int t = (threadIdx.x >= off) ? buf[threadIdx.x - off] : 0;
            __syncthreads();
            buf[threadIdx.x] += t;
            __syncthreads();
        }
        int excl = buf[threadIdx.x] - v;
        if (i < N_NODES) { offsets[i] = base + excl; cursor[i] = base + excl; }
        int tot = buf[1023];
        __syncthreads();
        base += tot;
    }
    if (threadIdx.x == 0) offsets[N_NODES] = base;
}

__global__ void fill_kernel(const int* __restrict__ edge_dst,
                            int* __restrict__ cursor, int* __restrict__ elist) {
    int e = blockIdx.x * 256 + threadIdx.x;
    if (e < N_EDGES) {
        int pos = atomicAdd(&cursor[edge_dst[e]], 1);
        elist[pos] = e;
    }
}

// ---------------- Kernel 3: per-node gather + W-proj + TP + output GEMM -----
// one block per node; W columns live in registers (loaded once per block)
__global__ __launch_bounds__(256) void gather_kernel(
    const int* __restrict__ offsets, const int* __restrict__ elist,
    const int* __restrict__ edge_src,
    const float* __restrict__ edge_attr,   // (E,4)
    const float* __restrict__ h2buf,       // (E,64)
    const float* __restrict__ feat_tbl,    // (N,320)
    const float* __restrict__ self_tbl,    // (N,320)
    const float* __restrict__ Wtp0,        // (64,128)
    const float* __restrict__ Wtp1,        // (64,128)
    const float* __restrict__ Wtp2,        // (64,64)
    const float* __restrict__ Wtp3,        // (64,64)
    const float* __restrict__ Wo0,         // (192,128)
    const float* __restrict__ Wo1,         // (192,64)
    float* __restrict__ out)               // (N,320)
{
    __shared__ float h2s[CHUNK][65];
    __shared__ float wsh[CHUNK * 384];     // w[e][u] at e*384+u
    __shared__ float fs[CHUNK][321];
    __shared__ float ys[CHUNK][4];
    __shared__ int   eids[CHUNK];
    __shared__ int   srcs[CHUNK];
    __shared__ float z[768];

    const int node = blockIdx.x;
    const int t = threadIdx.x;

    // ---- Wtp columns in registers: u0 = t for all, u1 = 256+t for t<128 ----
    float wc0[64], wc1[64];
    {
        const float* col0 = (t < 128) ? (Wtp0 + t) : (Wtp1 + (t - 128));
#pragma unroll
        for (int k = 0; k < 64; ++k) wc0[k] = col0[k * 128];
        const float* col1 = (t < 64) ? (Wtp2 + t) : (Wtp3 + (t - 64));
        if (t < 128) {
#pragma unroll
            for (int k = 0; k < 64; ++k) wc1[k] = col1[k * 64];
        }
    }

    // ---- per-thread output mapping for j in {t, t+256, t+512} ----
    // kind: 0=mid0a(w0*e0*y0) 1=mid0b(w3*dot/sqrt3) 2/else=mid1a/mid1b forms
    int wrow0, fidx0, yidx0, kind0;
    if (t < 128)      { kind0 = 0; wrow0 = t;                 fidx0 = t;   yidx0 = 0; }
    else if (t < 192) { kind0 = 1; wrow0 = 320 + (t - 128);   fidx0 = 128 + 3 * (t - 128); yidx0 = 0; }
    else { int r = t - 192, u = r / 3, i = r - 3 * u;
           kind0 = 2; wrow0 = 128 + u; fidx0 = u; yidx0 = 1 + i; }
    int r1 = t + 64, u1 = r1 / 3, i1 = r1 - 3 * u1;          // j1 = t+256, always mid1a
    const int wrow1 = 128 + u1, fidx1 = u1, yidx1 = 1 + i1;
    int wrow2, fidx2, yidx2;                                  // j2 = t+512
    if (t < 64) { int r = t + 320, u = r / 3, i = r - 3 * u;  // mid1a tail
                  wrow2 = 128 + u; fidx2 = u; yidx2 = 1 + i; }
    else        { int r = t - 64,  u = r / 3, i = r - 3 * u;  // mid1b
                  wrow2 = 256 + u; fidx2 = 128 + 3 * u + i; yidx2 = 0; }

    float acc0 = 0.f, acc1 = 0.f, acc2 = 0.f;
    const int beg = offsets[node], end = offsets[node + 1];

    for (int cb = beg; cb < end; cb += CHUNK) {
        const int ne = min(CHUNK, end - cb);
        if (t < ne) eids[t] = elist[cb + t];
        __syncthreads();
        if (t < ne) srcs[t] = edge_src[eids[t]];
        for (int x = t; x < ne * 64; x += 256) {
            int e = x >> 6, k = x & 63;
            h2s[e][k] = h2buf[(size_t)eids[e] * 64 + k];
        }
        for (int x = t; x < ne * 4; x += 256) {
            int e = x >> 2, i = x & 3;
            ys[e][i] = edge_attr[(size_t)eids[e] * 4 + i];
        }
        __syncthreads();
        // stage feat rows (needs srcs)
        for (int x = t; x < ne * 320; x += 256) {
            int e = x / 320, k = x - e * 320;
            fs[e][k] = feat_tbl[(size_t)srcs[e] * FEAT_W + k];
        }
        // ---- W projection from registers: w[e][u] = (h2[e].Wcol_u)/8 ----
        for (int e = 0; e < ne; ++e) {
            float s0 = 0.f;
#pragma unroll
            for (int k = 0; k < 64; ++k) s0 += h2s[e][k] * wc0[k];
            wsh[e * 384 + t] = s0 * 0.125f;
            if (t < 128) {
                float s1 = 0.f;
#pragma unroll
                for (int k = 0; k < 64; ++k) s1 += h2s[e][k] * wc1[k];
                wsh[e * 384 + 256 + t] = s1 * 0.125f;
            }
        }
        __syncthreads();

        // ---- accumulate tensor product ----
        for (int e = 0; e < ne; ++e) {
            const float* we = wsh + e * 384;
            if (kind0 == 1) {
                const float d = fs[e][fidx0] * ys[e][1] + fs[e][fidx0 + 1] * ys[e][2]
                              + fs[e][fidx0 + 2] * ys[e][3];
                acc0 += we[wrow0] * d * 0.5773502691896258f;  // 1/sqrt(3)
            } else {
                acc0 += we[wrow0] * fs[e][fidx0] * ys[e][yidx0];
            }
            acc1 += we[wrow1] * fs[e][fidx1] * ys[e][yidx1];
            acc2 += we[wrow2] * fs[e][fidx2] * ys[e][yidx2];
        }
        __syncthreads();   // before next chunk overwrites LDS
    }

    // ---- z row (includes 1/sqrt(16)) ----
    z[t]       = acc0 * 0.25f;
    z[t + 256] = acc1 * 0.25f;
    z[t + 512] = acc2 * 0.25f;
    __syncthreads();

    // ---- output GEMMs + rotation combine ----
    const float sA = 0.07216878364870323f;   // 1/sqrt(192)
    const float cR = 0.92387953251128674f;   // cos(pi/8)
    const float sR = 0.38268343236508978f;   // sin(pi/8)

    for (int jj = t; jj < 320; jj += 256) {
        float conv = 0.f;
        if (jj < 128) {
            for (int v = 0; v < 192; ++v) conv += z[v] * Wo0[v * 128 + jj];
        } else {
            const int r = jj - 128, u = r / 3, i = r - 3 * u;
            for (int v = 0; v < 128; ++v) conv += z[192 + v * 3 + i] * Wo1[v * 64 + u];
            for (int v = 0; v < 64; ++v)  conv += z[576 + v * 3 + i] * Wo1[(128 + v) * 64 + u];
        }
        conv *= sA;
        const float sv = self_tbl[(size_t)node * FEAT_W + jj];
        out[(size_t)node * FEAT_W + jj] = cR * sv + sR * conv;
    }
}

extern "C" void kernel_launch(void* const* d_in, const int* in_sizes, int n_in,
                              void* d_out, int out_size, void* d_ws, size_t ws_size,
                              hipStream_t stream) {
    const float* node_input = (const float*)d_in[0];
    const float* edge_attr  = (const float*)d_in[1];
    const float* esa        = (const float*)d_in[2];
    const float* Wa0  = (const float*)d_in[3];
    const float* Wa1  = (const float*)d_in[4];
    const float* Wb0  = (const float*)d_in[5];
    const float* Wb1  = (const float*)d_in[6];
    const float* M1   = (const float*)d_in[7];
    const float* M2   = (const float*)d_in[8];
    const float* Wtp0 = (const float*)d_in[9];
    const float* Wtp1 = (const float*)d_in[10];
    const float* Wtp2 = (const float*)d_in[11];
    const float* Wtp3 = (const float*)d_in[12];
    const float* Wo0  = (const float*)d_in[13];
    const float* Wo1  = (const float*)d_in[14];
    const int* edge_src = (const int*)d_in[15];
    const int* edge_dst = (const int*)d_in[16];
    float* out = (float*)d_out;

    float* feat_tbl = (float*)d_ws;                               // 10000*320
    float* self_tbl = feat_tbl + (size_t)N_NODES * FEAT_W;        // 10000*320
    float* h2buf    = self_tbl + (size_t)N_NODES * FEAT_W;        // 160000*64
    int*   counts   = (int*)(h2buf + (size_t)N_EDGES * 64);       // 10000
    int*   offsets  = counts + N_NODES;                           // 10001
    int*   cursor   = offsets + N_NODES + 1;                      // 10000
    int*   elist    = cursor + N_NODES;                           // 160000

    hipMemsetAsync(counts, 0, sizeof(int) * N_NODES, stream);

    node_transform<<<N_NODES, 256, 0, stream>>>(node_input, Wa0, Wa1, Wb0, Wb1,
                                                feat_tbl, self_tbl);
    mlp_kernel<<<N_EDGES / 4, 256, 0, stream>>>(esa, M1, M2, h2buf);
    count_kernel<<<(N_EDGES + 255) / 256, 256, 0, stream>>>(edge_dst, counts);
    scan_kernel<<<1, 1024, 0, stream>>>(counts, offsets, cursor);
    fill_kernel<<<(N_EDGES + 255) / 256, 256, 0, stream>>>(edge_dst, cursor, elist);
    gather_kernel<<<N_NODES, 256, 0, stream>>>(offsets, elist, edge_src,
                                               edge_attr, h2buf, feat_tbl, self_tbl,
                                               Wtp0, Wtp1, Wtp2, Wtp3, Wo0, Wo1, out);
}

// Round 5
// 1572.585 us; speedup vs baseline: 29.4705x; 1.0546x over previous
//
#include <hip/hip_runtime.h>
#include <hip/hip_bf16.h>

#define N_NODES 10000
#define N_EDGES 160000
#define FEAT_W 320
#define CHUNK 16

__device__ __forceinline__ float gelu_tanh(float x) {
    float x3 = x * x * x;
    float t = tanhf(0.7978845608028654f * (x + 0.044715f * x3));
    return 0.5f * x * (1.0f + t);
}

// ---------------- Kernel 1: node transforms (feat0/feat1/self0/self1) -------
// feat_tbl / self_tbl rows: [0..128) = mul0 part, [128..320) = mul1 part as u*3+i
__global__ __launch_bounds__(256) void node_transform(
    const float* __restrict__ node_input,
    const float* __restrict__ Wa0, const float* __restrict__ Wa1,
    const float* __restrict__ Wb0, const float* __restrict__ Wb1,
    float* __restrict__ feat_tbl, float* __restrict__ self_tbl)
{
    __shared__ float x[FEAT_W];
    const int node = blockIdx.x;
    const float* row = node_input + (size_t)node * FEAT_W;
    for (int t = threadIdx.x; t < FEAT_W; t += 256) x[t] = row[t];
    __syncthreads();

    for (int t = threadIdx.x; t < 640; t += 256) {
        const bool is_self = (t >= 320);
        const int idx = is_self ? t - 320 : t;
        float acc = 0.f;
        if (idx < 128) {
            const float* W = is_self ? Wb0 : Wa0;
            for (int v = 0; v < 128; ++v) acc += x[v] * W[v * 128 + idx];
            acc *= 0.08838834764831845f;  // 1/sqrt(128)
        } else {
            const int r = idx - 128;
            const int u = r / 3;
            const int i = r - 3 * u;
            const float* W = is_self ? Wb1 : Wa1;
            for (int v = 0; v < 64; ++v) acc += x[128 + v * 3 + i] * W[v * 64 + u];
            acc *= 0.125f;  // 1/sqrt(64)
        }
        float* outp = is_self ? self_tbl : feat_tbl;
        outp[(size_t)node * FEAT_W + idx] = acc;
    }
}

// ---------------- Kernel 2: per-edge MLP -> h2 ------------------------------
__global__ __launch_bounds__(256) void mlp_kernel(
    const float* __restrict__ esa,   // (E,8)
    const float* __restrict__ M1,    // (8,64)
    const float* __restrict__ M2,    // (64,64)
    float* __restrict__ h2buf)       // (E,64)
{
    __shared__ float sh[4][64];
    const int wave = threadIdx.x >> 6;
    const int lane = threadIdx.x & 63;
    const int e = blockIdx.x * 4 + wave;   // N_EDGES % 4 == 0

    const float* er = esa + (size_t)e * 8;
    float h = 0.f;
#pragma unroll
    for (int k = 0; k < 8; ++k) h += er[k] * M1[k * 64 + lane];
    h = gelu_tanh(h * 0.35355339059327373f);   // 1/sqrt(8)
    sh[wave][lane] = h;
    __syncthreads();

    float h2 = 0.f;
    for (int v = 0; v < 64; ++v) h2 += sh[wave][v] * M2[v * 64 + lane];
    h2 = gelu_tanh(h2 * 0.125f);               // 1/sqrt(64)
    h2buf[(size_t)e * 64 + lane] = h2;
}

// ---------------- CSR build -------------------------------------------------
__global__ void count_kernel(const int* __restrict__ edge_dst, int* __restrict__ counts) {
    int e = blockIdx.x * 256 + threadIdx.x;
    if (e < N_EDGES) atomicAdd(&counts[edge_dst[e]], 1);
}

__global__ __launch_bounds__(1024) void scan_kernel(
    const int* __restrict__ counts, int* __restrict__ offsets, int* __restrict__ cursor)
{
    __shared__ int buf[1024];
    int base = 0;
    for (int c = 0; c < 10; ++c) {            // 10*1024 >= 10000
        int i = c * 1024 + threadIdx.x;
        int v = (i < N_NODES) ? counts[i] : 0;
        buf[threadIdx.x] = v;
        __syncthreads();
        for (int off = 1; off < 1024; off <<= 1) {
            int t = (threadIdx.x >= off) ? buf[threadIdx.x - off] : 0;
            __syncthreads();
            buf[threadIdx.x] += t;
            __syncthreads();
        }
        int excl = buf[threadIdx.x] - v;
        if (i < N_NODES) { offsets[i] = base + excl; cursor[i] = base + excl; }
        int tot = buf[1023];
        __syncthreads();
        base += tot;
    }
    if (threadIdx.x == 0) offsets[N_NODES] = base;
}

__global__ void fill_kernel(const int* __restrict__ edge_dst,
                            int* __restrict__ cursor, int* __restrict__ elist) {
    int e = blockIdx.x * 256 + threadIdx.x;
    if (e < N_EDGES) {
        int pos = atomicAdd(&cursor[edge_dst[e]], 1);
        elist[pos] = e;
    }
}

// ---------------- Kernel 3: per-node gather + W-proj + TP + output GEMM -----
// one block per node; Wtp columns in registers; ILP-friendly 4-way dot chains
__global__ __launch_bounds__(256) void gather_kernel(
    const int* __restrict__ offsets, const int* __restrict__ elist,
    const int* __restrict__ edge_src,
    const float* __restrict__ edge_attr,   // (E,4)
    const float* __restrict__ h2buf,       // (E,64)
    const float* __restrict__ feat_tbl,    // (N,320)
    const float* __restrict__ self_tbl,    // (N,320)
    const float* __restrict__ Wtp0,        // (64,128)
    const float* __restrict__ Wtp1,        // (64,128)
    const float* __restrict__ Wtp2,        // (64,64)
    const float* __restrict__ Wtp3,        // (64,64)
    const float* __restrict__ Wo0,         // (192,128)
    const float* __restrict__ Wo1,         // (192,64)
    float* __restrict__ out)               // (N,320)
{
    __shared__ __align__(16) float h2s[CHUNK * 68];  // stride 68: 16B-aligned rows, odd-bank
    __shared__ float wsh[CHUNK * 384];               // w[e][u] at e*384+u
    __shared__ float ys[CHUNK][4];
    __shared__ int   eids[CHUNK];
    __shared__ int   srcs[CHUNK];
    __shared__ float z[768];

    const int node = blockIdx.x;
    const int t = threadIdx.x;

    // ---- Wtp columns in registers: u0 = t for all, u1 = 256+t for t<128 ----
    float wc0[64], wc1[64];
    {
        const float* col0 = (t < 128) ? (Wtp0 + t) : (Wtp1 + (t - 128));
#pragma unroll
        for (int k = 0; k < 64; ++k) wc0[k] = col0[k * 128];
        if (t < 128) {
            const float* col1 = (t < 64) ? (Wtp2 + t) : (Wtp3 + (t - 64));
#pragma unroll
            for (int k = 0; k < 64; ++k) wc1[k] = col1[k * 64];
        }
    }

    // ---- per-thread output mapping for j in {t, t+256, t+512} ----
    // kind0 (wave-uniform): 0=mid0a (waves0,1)  1=mid0b (wave2)  2=mid1a (wave3)
    int wrow0, fidx0, yidx0, kind0;
    if (t < 128)      { kind0 = 0; wrow0 = t;                 fidx0 = t;   yidx0 = 0; }
    else if (t < 192) { kind0 = 1; wrow0 = 320 + (t - 128);   fidx0 = 128 + 3 * (t - 128); yidx0 = 0; }
    else { int r = t - 192, u = r / 3, i = r - 3 * u;
           kind0 = 2; wrow0 = 128 + u; fidx0 = u; yidx0 = 1 + i; }
    int r1 = t + 64, u1 = r1 / 3, i1 = r1 - 3 * u1;          // j1 = t+256, always mid1a
    const int wrow1 = 128 + u1, fidx1 = u1, yidx1 = 1 + i1;
    int wrow2, fidx2, yidx2;                                  // j2 = t+512
    if (t < 64) { int r = t + 320, u = r / 3, i = r - 3 * u;  // mid1a tail
                  wrow2 = 128 + u; fidx2 = u; yidx2 = 1 + i; }
    else        { int r = t - 64,  u = r / 3, i = r - 3 * u;  // mid1b
                  wrow2 = 256 + u; fidx2 = 128 + 3 * u + i; yidx2 = 0; }

    float acc0 = 0.f, acc1 = 0.f, acc2 = 0.f;
    const int beg = offsets[node], end = offsets[node + 1];

    for (int cb = beg; cb < end; cb += CHUNK) {
        const int ne = min(CHUNK, end - cb);
        if (t < ne) eids[t] = elist[cb + t];
        __syncthreads();
        if (t < ne) srcs[t] = edge_src[eids[t]];
        for (int x = t; x < ne * 64; x += 256) {
            int e = x >> 6, k = x & 63;
            h2s[e * 68 + k] = h2buf[(size_t)eids[e] * 64 + k];
        }
        for (int x = t; x < ne * 4; x += 256) {
            int e = x >> 2, i = x & 3;
            ys[e][i] = edge_attr[(size_t)eids[e] * 4 + i];
        }
        __syncthreads();

        // ---- W projection, col0 (all threads): 4 independent FMA chains ----
        for (int e = 0; e < ne; ++e) {
            const float4* hp = (const float4*)(h2s + e * 68);
            float s0 = 0.f, s1 = 0.f, s2 = 0.f, s3 = 0.f;
#pragma unroll
            for (int q = 0; q < 16; ++q) {
                const float4 h = hp[q];
                s0 += h.x * wc0[4 * q + 0];
                s1 += h.y * wc0[4 * q + 1];
                s2 += h.z * wc0[4 * q + 2];
                s3 += h.w * wc0[4 * q + 3];
            }
            wsh[e * 384 + t] = ((s0 + s1) + (s2 + s3)) * 0.125f;  // 1/sqrt(64)
        }
        // ---- col1 (waves 0,1 only; wave-uniform branch) ----
        if (t < 128) {
            for (int e = 0; e < ne; ++e) {
                const float4* hp = (const float4*)(h2s + e * 68);
                float s0 = 0.f, s1 = 0.f, s2 = 0.f, s3 = 0.f;
#pragma unroll
                for (int q = 0; q < 16; ++q) {
                    const float4 h = hp[q];
                    s0 += h.x * wc1[4 * q + 0];
                    s1 += h.y * wc1[4 * q + 1];
                    s2 += h.z * wc1[4 * q + 2];
                    s3 += h.w * wc1[4 * q + 3];
                }
                wsh[e * 384 + 256 + t] = ((s0 + s1) + (s2 + s3)) * 0.125f;
            }
        }
        __syncthreads();

        // ---- accumulate tensor product (feat read direct from L2-hot table) ----
        for (int e = 0; e < ne; ++e) {
            const float* we = wsh + e * 384;
            const float* fr = feat_tbl + (size_t)srcs[e] * FEAT_W;
            if (kind0 == 1) {
                const float d = fr[fidx0] * ys[e][1] + fr[fidx0 + 1] * ys[e][2]
                              + fr[fidx0 + 2] * ys[e][3];
                acc0 += we[wrow0] * d * 0.5773502691896258f;  // 1/sqrt(3)
            } else {
                acc0 += we[wrow0] * fr[fidx0] * ys[e][yidx0];
            }
            acc1 += we[wrow1] * fr[fidx1] * ys[e][yidx1];
            acc2 += we[wrow2] * fr[fidx2] * ys[e][yidx2];
        }
        __syncthreads();   // before next chunk overwrites LDS
    }

    // ---- z row (includes 1/sqrt(16)) ----
    z[t]       = acc0 * 0.25f;
    z[t + 256] = acc1 * 0.25f;
    z[t + 512] = acc2 * 0.25f;
    __syncthreads();

    // ---- output GEMMs + rotation combine ----
    const float sA = 0.07216878364870323f;   // 1/sqrt(192)
    const float cR = 0.92387953251128674f;   // cos(pi/8)
    const float sR = 0.38268343236508978f;   // sin(pi/8)

    for (int jj = t; jj < 320; jj += 256) {
        float conv = 0.f;
        if (jj < 128) {
            for (int v = 0; v < 192; ++v) conv += z[v] * Wo0[v * 128 + jj];
        } else {
            const int r = jj - 128, u = r / 3, i = r - 3 * u;
            for (int v = 0; v < 128; ++v) conv += z[192 + v * 3 + i] * Wo1[v * 64 + u];
            for (int v = 0; v < 64; ++v)  conv += z[576 + v * 3 + i] * Wo1[(128 + v) * 64 + u];
        }
        conv *= sA;
        const float sv = self_tbl[(size_t)node * FEAT_W + jj];
        out[(size_t)node * FEAT_W + jj] = cR * sv + sR * conv;
    }
}

extern "C" void kernel_launch(void* const* d_in, const int* in_sizes, int n_in,
                              void* d_out, int out_size, void* d_ws, size_t ws_size,
                              hipStream_t stream) {
    const float* node_input = (const float*)d_in[0];
    const float* edge_attr  = (const float*)d_in[1];
    const float* esa        = (const float*)d_in[2];
    const float* Wa0  = (const float*)d_in[3];
    const float* Wa1  = (const float*)d_in[4];
    const float* Wb0  = (const float*)d_in[5];
    const float* Wb1  = (const float*)d_in[6];
    const float* M1   = (const float*)d_in[7];
    const float* M2   = (const float*)d_in[8];
    const float* Wtp0 = (const float*)d_in[9];
    const float* Wtp1 = (const float*)d_in[10];
    const float* Wtp2 = (const float*)d_in[11];
    const float* Wtp3 = (const float*)d_in[12];
    const float* Wo0  = (const float*)d_in[13];
    const float* Wo1  = (const float*)d_in[14];
    const int* edge_src = (const int*)d_in[15];
    const int* edge_dst = (const int*)d_in[16];
    float* out = (float*)d_out;

    float* feat_tbl = (float*)d_ws;                               // 10000*320
    float* self_tbl = feat_tbl + (size_t)N_NODES * FEAT_W;        // 10000*320
    float* h2buf    = self_tbl + (size_t)N_NODES * FEAT_W;        // 160000*64
    int*   counts   = (int*)(h2buf + (size_t)N_EDGES * 64);       // 10000
    int*   offsets  = counts + N_NODES;                           // 10001
    int*   cursor   = offsets + N_NODES + 1;                      // 10000
    int*   elist    = cursor + N_NODES;                           // 160000

    hipMemsetAsync(counts, 0, sizeof(int) * N_NODES, stream);

    node_transform<<<N_NODES, 256, 0, stream>>>(node_input, Wa0, Wa1, Wb0, Wb1,
                                                feat_tbl, self_tbl);
    mlp_kernel<<<N_EDGES / 4, 256, 0, stream>>>(esa, M1, M2, h2buf);
    count_kernel<<<(N_EDGES + 255) / 256, 256, 0, stream>>>(edge_dst, counts);
    scan_kernel<<<1, 1024, 0, stream>>>(counts, offsets, cursor);
    fill_kernel<<<(N_EDGES + 255) / 256, 256, 0, stream>>>(edge_dst, cursor, elist);
    gather_kernel<<<N_NODES, 256, 0, stream>>>(offsets, elist, edge_src,
                                               edge_attr, h2buf, feat_tbl, self_tbl,
                                               Wtp0, Wtp1, Wtp2, Wtp3, Wo0, Wo1, out);
}

// Round 7
// 806.951 us; speedup vs baseline: 57.4320x; 1.9488x over previous
//
#include <hip/hip_runtime.h>
#include <hip/hip_bf16.h>

#define N_NODES 10000
#define N_EDGES 160000
#define FEAT_W 320
#define CHUNK 16

__device__ __forceinline__ float gelu_tanh(float x) {
    float x3 = x * x * x;
    float t = tanhf(0.7978845608028654f * (x + 0.044715f * x3));
    return 0.5f * x * (1.0f + t);
}

// ---------------- Kernel 1: node transforms, 8 nodes/block ------------------
// feat_tbl / self_tbl rows: [0..128) = mul0 part, [128..320) = mul1 part as u*3+i
__global__ __launch_bounds__(256) void node_transform(
    const float* __restrict__ node_input,
    const float* __restrict__ Wa0, const float* __restrict__ Wa1,
    const float* __restrict__ Wb0, const float* __restrict__ Wb1,
    float* __restrict__ feat_tbl, float* __restrict__ self_tbl)
{
    __shared__ float x[8][FEAT_W];         // 10.24 KB
    const int node0 = blockIdx.x * 8;
    const int t = threadIdx.x;
    for (int q = t; q < 8 * FEAT_W / 4; q += 256)
        ((float4*)x)[q] = ((const float4*)(node_input + (size_t)node0 * FEAT_W))[q];
    __syncthreads();

    for (int g = 0; g < 3; ++g) {
        const int oidx = t + g * 256;
        if (oidx >= 640) break;
        const bool is_self = (oidx >= 320);
        const int idx = is_self ? oidx - 320 : oidx;
        float acc[8] = {0, 0, 0, 0, 0, 0, 0, 0};
        if (idx < 128) {
            const float* W = is_self ? Wb0 : Wa0;
            for (int v = 0; v < 128; ++v) {
                const float wv = W[v * 128 + idx];
#pragma unroll
                for (int n = 0; n < 8; ++n) acc[n] += x[n][v] * wv;
            }
#pragma unroll
            for (int n = 0; n < 8; ++n) acc[n] *= 0.08838834764831845f;  // 1/sqrt(128)
        } else {
            const int r = idx - 128, u = r / 3, i = r - 3 * u;
            const float* W = is_self ? Wb1 : Wa1;
            for (int v = 0; v < 64; ++v) {
                const float wv = W[v * 64 + u];
#pragma unroll
                for (int n = 0; n < 8; ++n) acc[n] += x[n][128 + v * 3 + i] * wv;
            }
#pragma unroll
            for (int n = 0; n < 8; ++n) acc[n] *= 0.125f;                // 1/sqrt(64)
        }
        float* outp = is_self ? self_tbl : feat_tbl;
#pragma unroll
        for (int n = 0; n < 8; ++n)
            outp[(size_t)(node0 + n) * FEAT_W + idx] = acc[n];
    }
}

// ---------------- Kernel 2: per-edge MLP -> h2 ------------------------------
__global__ __launch_bounds__(256) void mlp_kernel(
    const float* __restrict__ esa,   // (E,8)
    const float* __restrict__ M1,    // (8,64)
    const float* __restrict__ M2,    // (64,64)
    float* __restrict__ h2buf)       // (E,64)
{
    __shared__ float sh[4][64];
    const int wave = threadIdx.x >> 6;
    const int lane = threadIdx.x & 63;
    const int e = blockIdx.x * 4 + wave;   // N_EDGES % 4 == 0

    const float* er = esa + (size_t)e * 8;
    float h = 0.f;
#pragma unroll
    for (int k = 0; k < 8; ++k) h += er[k] * M1[k * 64 + lane];
    h = gelu_tanh(h * 0.35355339059327373f);   // 1/sqrt(8)
    sh[wave][lane] = h;
    __syncthreads();

    float h2 = 0.f;
    for (int v = 0; v < 64; ++v) h2 += sh[wave][v] * M2[v * 64 + lane];
    h2 = gelu_tanh(h2 * 0.125f);               // 1/sqrt(64)
    h2buf[(size_t)e * 64 + lane] = h2;
}

// ---------------- CSR build -------------------------------------------------
__global__ void count_kernel(const int* __restrict__ edge_dst, int* __restrict__ counts) {
    int e = blockIdx.x * 256 + threadIdx.x;
    if (e < N_EDGES) atomicAdd(&counts[edge_dst[e]], 1);
}

__global__ __launch_bounds__(1024) void scan_kernel(
    const int* __restrict__ counts, int* __restrict__ offsets, int* __restrict__ cursor)
{
    __shared__ int buf[1024];
    int base = 0;
    for (int c = 0; c < 10; ++c) {            // 10*1024 >= 10000
        int i = c * 1024 + threadIdx.x;
        int v = (i < N_NODES) ? counts[i] : 0;
        buf[threadIdx.x] = v;
        __syncthreads();
        for (int off = 1; off < 1024; off <<= 1) {
            int t = (threadIdx.x >= off) ? buf[threadIdx.x - off] : 0;
            __syncthreads();
            buf[threadIdx.x] += t;
            __syncthreads();
        }
        int excl = buf[threadIdx.x] - v;
        if (i < N_NODES) { offsets[i] = base + excl; cursor[i] = base + excl; }
        int tot = buf[1023];
        __syncthreads();
        base += tot;
    }
    if (threadIdx.x == 0) offsets[N_NODES] = base;
}

__global__ void fill_kernel(const int* __restrict__ edge_dst,
                            int* __restrict__ cursor, int* __restrict__ elist) {
    int e = blockIdx.x * 256 + threadIdx.x;
    if (e < N_EDGES) {
        int pos = atomicAdd(&cursor[edge_dst[e]], 1);
        elist[pos] = e;
    }
}

// ---- agg-column j -> (dot-form?, w-row, feat-idx, y-idx) -------------------
__device__ __forceinline__ void map_j(int j, int& kind, int& wrow, int& fidx, int& yidx) {
    if (j < 128)      { kind = 0; wrow = j;               fidx = j;               yidx = 0; }
    else if (j < 192) { kind = 1; wrow = 320 + (j - 128); fidx = 128 + 3 * (j - 128); yidx = 0; }
    else if (j < 576) { int r = j - 192, u = r / 3, i = r - 3 * u;
                        kind = 0; wrow = 128 + u; fidx = u;               yidx = 1 + i; }
    else              { int r = j - 576, u = r / 3, i = r - 3 * u;
                        kind = 0; wrow = 256 + u; fidx = 128 + 3 * u + i; yidx = 0; }
}

// ---------------- Kernel 3: fused gather: proj + TP + out-GEMM --------------
// 384 threads/block, one block per node. Thread t owns weight column u=t.
// Weights read from global (L1/L2-hot, 98 KB total), k-outer / 16-edge-unrolled
// inner -> 16 FMAs per weight load, 16 independent acc chains.
__global__ __launch_bounds__(384) void gather_kernel(
    const int* __restrict__ offsets, const int* __restrict__ elist,
    const int* __restrict__ edge_src,
    const float* __restrict__ edge_attr,   // (E,4)
    const float* __restrict__ h2buf,       // (E,64)
    const float* __restrict__ feat_tbl,    // (N,320)
    const float* __restrict__ self_tbl,    // (N,320)
    const float* __restrict__ Wtp0,        // (64,128)
    const float* __restrict__ Wtp1,        // (64,128)
    const float* __restrict__ Wtp2,        // (64,64)
    const float* __restrict__ Wtp3,        // (64,64)
    const float* __restrict__ Wo0,         // (192,128)
    const float* __restrict__ Wo1,         // (192,64)
    float* __restrict__ out)               // (N,320)
{
    __shared__ float h2s[CHUNK * 68];      // 4.35 KB (stride 68 padding)
    __shared__ float ws[CHUNK * 384];      // 24.6 KB  w[e][u] at e*384+u
    __shared__ float ys[CHUNK][4];
    __shared__ int   eids[CHUNK];
    __shared__ int   srcs[CHUNK];
    __shared__ float z[768];               // 3 KB

    const int node = blockIdx.x;
    const int t = threadIdx.x;             // 0..383

    // weight column for this thread (wave-uniform branch selection)
    const float* wcol; int wstride;
    if (t < 128)      { wcol = Wtp0 + t;         wstride = 128; }
    else if (t < 256) { wcol = Wtp1 + (t - 128); wstride = 128; }
    else if (t < 320) { wcol = Wtp2 + (t - 256); wstride = 64;  }
    else              { wcol = Wtp3 + (t - 320); wstride = 64;  }

    // TP output mapping for j = t and j = t + 384
    int kind0, wrow0, fidx0, yidx0, kind1, wrow1, fidx1, yidx1;
    map_j(t, kind0, wrow0, fidx0, yidx0);
    map_j(t + 384, kind1, wrow1, fidx1, yidx1);

    float acc0 = 0.f, acc1 = 0.f;
    const int beg = offsets[node], end = offsets[node + 1];

    for (int cb = beg; cb < end; cb += CHUNK) {
        const int ne = min(CHUNK, end - cb);
        if (t < ne) eids[t] = elist[cb + t];
        __syncthreads();
        if (t < ne) {
            srcs[t] = edge_src[eids[t]];
            ((float4*)ys)[t] = ((const float4*)edge_attr)[eids[t]];
        }
        // stage h2 rows (zero-fill e >= ne so proj acc stays finite)
        for (int x = t; x < CHUNK * 64; x += 384) {
            int e = x >> 6, k = x & 63;
            h2s[e * 68 + k] = (e < ne) ? h2buf[(size_t)eids[e] * 64 + k] : 0.f;
        }
        __syncthreads();

        // ---- projection: w[e][t] = (h2[e] . wcol)/8, 16-edge unrolled ----
        {
            float a[CHUNK];
#pragma unroll
            for (int e = 0; e < CHUNK; ++e) a[e] = 0.f;
            for (int k = 0; k < 64; ++k) {
                const float wv = wcol[k * wstride];
#pragma unroll
                for (int e = 0; e < CHUNK; ++e) a[e] += h2s[e * 68 + k] * wv;
            }
#pragma unroll
            for (int e = 0; e < CHUNK; ++e)
                if (e < ne) ws[e * 384 + t] = a[e] * 0.125f;   // 1/sqrt(64)
        }
        __syncthreads();

        // ---- tensor product accumulate (feat from L2-hot table) ----
        for (int e = 0; e < ne; ++e) {
            const float* we = ws + e * 384;
            const float* fr = feat_tbl + (size_t)srcs[e] * FEAT_W;
            if (kind0 == 1) {   // wave-uniform: exactly wave 2 (t in [128,192))
                const float d = fr[fidx0] * ys[e][1] + fr[fidx0 + 1] * ys[e][2]
                              + fr[fidx0 + 2] * ys[e][3];
                acc0 += we[wrow0] * d * 0.5773502691896258f;   // 1/sqrt(3)
            } else {
                acc0 += we[wrow0] * fr[fidx0] * ys[e][yidx0];
            }
            acc1 += we[wrow1] * fr[fidx1] * ys[e][yidx1];
        }
        __syncthreads();   // before next chunk overwrites LDS
    }

    // ---- z row (includes 1/sqrt(16)) ----
    z[t]       = acc0 * 0.25f;
    z[t + 384] = acc1 * 0.25f;
    __syncthreads();

    // ---- output GEMM + rotation combine ----
    const float sA = 0.07216878364870323f;   // 1/sqrt(192)
    const float cR = 0.92387953251128674f;   // cos(pi/8)
    const float sR = 0.38268343236508978f;   // sin(pi/8)

    if (t < 320) {
        float conv = 0.f;
        if (t < 128) {
            for (int v = 0; v < 192; ++v) conv += z[v] * Wo0[v * 128 + t];
        } else {
            const int r = t - 128, u = r / 3, i = r - 3 * u;
            for (int v = 0; v < 128; ++v) conv += z[192 + v * 3 + i] * Wo1[v * 64 + u];
            for (int v = 0; v < 64; ++v)  conv += z[576 + v * 3 + i] * Wo1[(128 + v) * 64 + u];
        }
        conv *= sA;
        const float sv = self_tbl[(size_t)node * FEAT_W + t];
        out[(size_t)node * FEAT_W + t] = cR * sv + sR * conv;
    }
}

extern "C" void kernel_launch(void* const* d_in, const int* in_sizes, int n_in,
                              void* d_out, int out_size, void* d_ws, size_t ws_size,
                              hipStream_t stream) {
    const float* node_input = (const float*)d_in[0];
    const float* edge_attr  = (const float*)d_in[1];
    const float* esa        = (const float*)d_in[2];
    const float* Wa0  = (const float*)d_in[3];
    const float* Wa1  = (const float*)d_in[4];
    const float* Wb0  = (const float*)d_in[5];
    const float* Wb1  = (const float*)d_in[6];
    const float* M1   = (const float*)d_in[7];
    const float* M2   = (const float*)d_in[8];
    const float* Wtp0 = (const float*)d_in[9];
    const float* Wtp1 = (const float*)d_in[10];
    const float* Wtp2 = (const float*)d_in[11];
    const float* Wtp3 = (const float*)d_in[12];
    const float* Wo0  = (const float*)d_in[13];
    const float* Wo1  = (const float*)d_in[14];
    const int* edge_src = (const int*)d_in[15];
    const int* edge_dst = (const int*)d_in[16];
    float* out = (float*)d_out;

    // ws usage: 16.64M floats + 0.34M ints ~= 68 MB (proven in R2-R5)
    float* feat_tbl = (float*)d_ws;                               // 10000*320
    float* self_tbl = feat_tbl + (size_t)N_NODES * FEAT_W;        // 10000*320
    float* h2buf    = self_tbl + (size_t)N_NODES * FEAT_W;        // 160000*64
    int*   counts   = (int*)(h2buf + (size_t)N_EDGES * 64);       // 10000
    int*   offsets  = counts + N_NODES;                           // 10001
    int*   cursor   = offsets + N_NODES + 1;                      // 10000
    int*   elist    = cursor + N_NODES;                           // 160000

    hipMemsetAsync(counts, 0, sizeof(int) * N_NODES, stream);

    node_transform<<<N_NODES / 8, 256, 0, stream>>>(node_input, Wa0, Wa1, Wb0, Wb1,
                                                    feat_tbl, self_tbl);
    mlp_kernel<<<N_EDGES / 4, 256, 0, stream>>>(esa, M1, M2, h2buf);
    count_kernel<<<N_EDGES / 256, 256, 0, stream>>>(edge_dst, counts);
    scan_kernel<<<1, 1024, 0, stream>>>(counts, offsets, cursor);
    fill_kernel<<<N_EDGES / 256, 256, 0, stream>>>(edge_dst, cursor, elist);
    gather_kernel<<<N_NODES, 384, 0, stream>>>(offsets, elist, edge_src,
                                               edge_attr, h2buf, feat_tbl, self_tbl,
                                               Wtp0, Wtp1, Wtp2, Wtp3, Wo0, Wo1, out);
}